// Round 5
// baseline (93.296 us; speedup 1.0000x reference)
//
#include <hip/hip_runtime.h>
#include <math.h>

// Problem constants (Spline_Fitting): B=2, S=128, D=256, H=8, E=32
constexpr int BB = 2;
constexpr int SS = 128;
constexpr int DD = 256;
constexpr int HH = 8;
constexpr int EE = 32;
constexpr int PKG = 132;  // per-row package: 32 sorted + 33 P1 + 33 P2 + 33 P3 (131, pad 132)

// ---------------------------------------------------------------------------
// KA: x[bh][s][e] = softmax_E(inp @ w_in^T + b_in), PLUS per-row sorted values
// + inclusive prefix sums of (s, s^2, s^3) -> pkg.
// Sort: 32-lane bitonic via __shfl_xor; scans: Hillis-Steele via __shfl_up.
// ---------------------------------------------------------------------------
__global__ __launch_bounds__(256) void spline_ka(
    const float* __restrict__ inp,   // (B,S,D)
    const float* __restrict__ w_in,  // (D,D)
    const float* __restrict__ b_in,  // (D,)
    float* __restrict__ xs_out,      // (16,128,32)
    float* __restrict__ pkg_g)       // (16,128,PKG)
{
  const int row = blockIdx.x;        // b*S + s
  const int e = threadIdx.x;         // 0..255
  __shared__ float in_row[DD];
  __shared__ float vals[DD];
  __shared__ float exps[DD];

  in_row[e] = inp[row * DD + e];
  __syncthreads();

  const float* wr = w_in + e * DD;
  float acc = b_in[e];
#pragma unroll 8
  for (int d = 0; d < DD; d += 4) {
    const float4 w4 = *reinterpret_cast<const float4*>(wr + d);
    acc = fmaf(in_row[d + 0], w4.x, acc);
    acc = fmaf(in_row[d + 1], w4.y, acc);
    acc = fmaf(in_row[d + 2], w4.z, acc);
    acc = fmaf(in_row[d + 3], w4.w, acc);
  }
  vals[e] = acc;
  __syncthreads();

  const int h = e >> 5, base = h * EE, l = e & 31;
  float mx = -1e30f;
#pragma unroll
  for (int k = 0; k < EE; ++k) mx = fmaxf(mx, vals[base + k]);
  const float ex = __expf(acc - mx);
  exps[e] = ex;
  __syncthreads();
  float sum = 0.f;
#pragma unroll
  for (int k = 0; k < EE; ++k) sum += exps[base + k];
  const float x = ex / sum;

  const int b = row >> 7, s = row & 127;
  const int bh = b * HH + h;
  xs_out[(bh * SS + s) * EE + l] = x;

  // ---- bitonic sort ascending across the 32-lane group ----
  float v = x;
#pragma unroll
  for (int k = 2; k <= 32; k <<= 1) {
#pragma unroll
    for (int j = k >> 1; j > 0; j >>= 1) {
      const float o = __shfl_xor(v, j, 32);
      const bool up = ((l & k) == 0);
      const bool tmin = (((l & j) == 0) == up);
      v = tmin ? fminf(v, o) : fmaxf(v, o);
    }
  }
  // ---- inclusive scans of v, v^2, v^3 ----
  float i1 = v, i2 = v * v, i3 = v * v * v;
#pragma unroll
  for (int j = 1; j < 32; j <<= 1) {
    const float o1 = __shfl_up(i1, j, 32);
    const float o2 = __shfl_up(i2, j, 32);
    const float o3 = __shfl_up(i3, j, 32);
    if (l >= j) { i1 += o1; i2 += o2; i3 += o3; }
  }
  float* pk = pkg_g + (bh * SS + s) * PKG;
  pk[l] = v;              // sorted values s[0..31]
  pk[32 + l + 1] = i1;    // P1[1..32]
  pk[65 + l + 1] = i2;    // P2[1..32]
  pk[98 + l + 1] = i3;    // P3[1..32]
  if (l == 0) { pk[32] = 0.f; pk[65] = 0.f; pk[98] = 0.f; }
}

// ---------------------------------------------------------------------------
// KB3: fused scores + softmax + PV + output GEMV. Block = (b,i), 1024 threads:
// h = tid>>7 (head), j = tid&127. Per (h,j): sorted-prefix score eval
// (binary search, O(E log E)), per-head 128-wide softmax (shfl + LDS), PV with
// coalesced L2 reads of xs_g -> yrow[256] in LDS, then out = yrow @ w_out^T
// + b_out with the 256-dot split 4 ways across threads.
// ---------------------------------------------------------------------------
__global__ __launch_bounds__(1024) void spline_kb3(
    const float* __restrict__ xs_g,   // (16,128,32)
    const float* __restrict__ pkg_g,  // (16,128,PKG)
    const float* __restrict__ w_out,  // (D,D)
    const float* __restrict__ b_out,  // (D,)
    float* __restrict__ out)          // (B,S,D)
{
  const int i = blockIdx.x;           // 0..127
  const int b = blockIdx.y;           // 0..1
  const int tid = threadIdx.x;        // 0..1023
  const int h = tid >> 7;             // 0..7
  const int j = tid & 127;            // 0..127
  const int bh = b * HH + h;

  __shared__ float pkv[HH * PKG];     // 8 row-i packages (stride 132)
  __shared__ float at[HH * SS];       // exp(logit - mx) per (h,j)
  __shared__ float part[1024];        // PV partials, reused for GEMV partials
  __shared__ float yrow[DD];          // attention output row (256)
  __shared__ float wredm[16];         // per-(h,wave) max
  __shared__ float wreds[16];         // per-(h,wave) sum

  // stage all 8 head packages for row i
  for (int idx = tid; idx < HH * 131; idx += 1024) {
    const int hh = idx / 131, kk = idx - hh * 131;
    pkv[hh * PKG + kk] = pkg_g[((b * HH + hh) * SS + i) * PKG + kk];
  }
  // own row j of head bh -> registers (L2-resident, static indices)
  float vreg[EE];
  {
    const float4* vr4 = (const float4*)(xs_g + (bh * SS + j) * EE);
    float4* vv = (float4*)vreg;
#pragma unroll
    for (int k = 0; k < 8; ++k) vv[k] = vr4[k];
  }
  __syncthreads();

  const float* sI = pkv + h * PKG;  // [32] sorted row i of head bh
  const float* P1 = sI + 32;        // [33]
  const float* P2 = sI + 65;        // [33]
  const float* P3 = sI + 98;        // [33]
  const float T1 = P1[32];

  float A = 0.f, Bq = 0.f, C = 0.f, Dg = 0.f, sv = 0.f;
#pragma unroll
  for (int bb = 0; bb < EE; ++bb) {
    const float v = vreg[bb];
    sv += v;
    int idx = 0;
#pragma unroll
    for (int off = 16; off > 0; off >>= 1)
      if (sI[idx + off - 1] <= v) idx += off;   // probe tree: broadcast-ish banks
    if (sI[idx] <= v) ++idx;                    // idx = #{u <= v} in [0,32]
    const float g1 = P1[idx], g2 = P2[idx], g3 = P3[idx];
    const float v2 = v * v;
    const float fi = (float)idx - 32.0f;
    A = fmaf(v, g2, A);            // v * P2[idx]
    Bq = fmaf(v2, T1 - g1, Bq);    // v^2 * (T1 - P1[idx])
    C = fmaf(v2 * v, fi, C);       // v^3 * (idx - 32)
    Dg += g3;                      // P3[idx]
  }
  const float sumF = fmaf(0.5f, A + Bq, (C - Dg) * (1.f / 6.f));
  const float logit = (fmaf(T1, sv, sumF) + (float)(EE * EE)) * (1.0f / (float)EE);

  // ---- per-head softmax over 128 j's (2 waves per head) ----
  float mx = logit;
#pragma unroll
  for (int off = 32; off; off >>= 1) mx = fmaxf(mx, __shfl_xor(mx, off));
  if ((tid & 63) == 0) wredm[tid >> 6] = mx;    // tid>>6 == h*2 + wave
  __syncthreads();
  mx = fmaxf(wredm[h * 2], wredm[h * 2 + 1]);
  const float ex = __expf(logit - mx);
  at[tid] = ex;                                  // at[h*128 + j]
  float sm = ex;
#pragma unroll
  for (int off = 32; off; off >>= 1) sm += __shfl_xor(sm, off);
  if ((tid & 63) == 0) wreds[tid >> 6] = sm;
  __syncthreads();

  // ---- PV: e = tid&31, q = (tid>>5)&3; coalesced global xs reads ----
  {
    const int e = tid & 31, q = (tid >> 5) & 3;
    const float* xb = xs_g + (bh * SS + q * 32) * EE + e;
    const float* ab = at + h * SS + q * 32;
    float o = 0.f;
#pragma unroll
    for (int jj = 0; jj < 32; ++jj)
      o = fmaf(ab[jj], xb[jj * EE], o);
    part[tid] = o;
  }
  __syncthreads();
  if (tid < DD) {
    const int hh = tid >> 5, ee = tid & 31;
    const float rs = 1.0f / (wreds[hh * 2] + wreds[hh * 2 + 1]);
    const float* pp = part + hh * SS + ee;
    yrow[tid] = (pp[0] + pp[32] + pp[64] + pp[96]) * rs;
  }
  __syncthreads();

  // ---- out = yrow @ w_out^T + b_out; dot split 4 ways over d ----
  {
    const int f = tid & 255, seg = tid >> 8;
    const float* wr = w_out + f * DD + seg * 64;
    const float* yb = yrow + seg * 64;
    float accp = 0.f;
#pragma unroll
    for (int k = 0; k < 64; k += 4) {
      const float4 w4 = *reinterpret_cast<const float4*>(wr + k);
      accp = fmaf(yb[k + 0], w4.x, accp);
      accp = fmaf(yb[k + 1], w4.y, accp);
      accp = fmaf(yb[k + 2], w4.z, accp);
      accp = fmaf(yb[k + 3], w4.w, accp);
    }
    part[tid] = accp;  // reuse
  }
  __syncthreads();
  if (tid < DD) {
    out[(b * SS + i) * DD + tid] =
        b_out[tid] + part[tid] + part[256 + tid] + part[512 + tid] + part[768 + tid];
  }
}

extern "C" void kernel_launch(void* const* d_in, const int* in_sizes, int n_in,
                              void* d_out, int out_size, void* d_ws, size_t ws_size,
                              hipStream_t stream) {
  const float* inp   = (const float*)d_in[0];  // (2,128,256)
  const float* w_in  = (const float*)d_in[1];  // (256,256)
  const float* b_in  = (const float*)d_in[2];  // (256,)
  const float* w_out = (const float*)d_in[3];  // (256,256)
  const float* b_out = (const float*)d_in[4];  // (256,)
  float* out = (float*)d_out;                  // (2,128,256)

  float* ws_x   = (float*)d_ws;                 // (16,128,32)   65536 floats
  float* ws_pkg = ws_x + BB * HH * SS * EE;     // (16,128,132) 270336 floats

  spline_ka<<<BB * SS, 256, 0, stream>>>(inp, w_in, b_in, ws_x, ws_pkg);
  spline_kb3<<<dim3(SS, BB), 1024, 0, stream>>>(ws_x, ws_pkg, w_out, b_out, out);
}